// Round 11
// baseline (227.588 us; speedup 1.0000x reference)
//
#include <hip/hip_runtime.h>

#define N_NODES 50000
#define PADROWS 50176   // 392*128, branchless A loads
#define N_EDGES 600000
#define NPART 196   // ceil(50000/256)

using f32x4  = __attribute__((ext_vector_type(4))) float;
using bf16x8 = __attribute__((ext_vector_type(8))) short;

__device__ inline ushort f2bf(float f) {
    uint32_t u = __builtin_bit_cast(uint32_t, f);
    uint32_t r = (u + 0x7FFFu + ((u >> 16) & 1u)) >> 16;
    return (ushort)r;
}
__device__ inline float bf2f(ushort h) {
    uint32_t u = ((uint32_t)h) << 16;
    return __builtin_bit_cast(float, u);
}

// ---------------------------------------------------------------- zero

__global__ void zero2_kernel(int* __restrict__ a, int* __restrict__ b) {
    int i = blockIdx.x * 256 + threadIdx.x;
    if (i < N_NODES) { a[i] = 0; b[i] = 0; }
}

// ---------------------------------------------------------------- CSR build

__global__ void count_kernel(const int* __restrict__ dst, int* __restrict__ cnt) {
    int e = blockIdx.x * blockDim.x + threadIdx.x;
    if (e < N_EDGES) atomicAdd(&cnt[dst[e]], 1);
}

__global__ void scan_part(const int* __restrict__ cnt, int* __restrict__ partials) {
    __shared__ int sm[256];
    int b = blockIdx.x, t = threadIdx.x;
    int i = b * 256 + t;
    sm[t] = (i < N_NODES) ? cnt[i] : 0;
    __syncthreads();
    for (int off = 128; off > 0; off >>= 1) {
        if (t < off) sm[t] += sm[t + off];
        __syncthreads();
    }
    if (t == 0) partials[b] = sm[0];
}

__global__ void scan_mid(const int* __restrict__ partials, int* __restrict__ offsets) {
    __shared__ int sm[256];
    int t = threadIdx.x;
    int v = (t < NPART) ? partials[t] : 0;
    sm[t] = v;
    __syncthreads();
    for (int off = 1; off < 256; off <<= 1) {
        int u = (t >= off) ? sm[t - off] : 0;
        __syncthreads();
        sm[t] += u;
        __syncthreads();
    }
    if (t < NPART) offsets[t] = sm[t] - v;   // exclusive prefix
}

__global__ void scan_final(const int* __restrict__ cnt, const int* __restrict__ offsets,
                           int* __restrict__ rowptr) {
    __shared__ int sm[256];
    int b = blockIdx.x, t = threadIdx.x;
    int i = b * 256 + t;
    int v = (i < N_NODES) ? cnt[i] : 0;
    sm[t] = v;
    __syncthreads();
    for (int off = 1; off < 256; off <<= 1) {
        int u = (t >= off) ? sm[t - off] : 0;
        __syncthreads();
        sm[t] += u;
        __syncthreads();
    }
    if (i < N_NODES) rowptr[i + 1] = sm[t] + offsets[b];
    if (i == 0) rowptr[0] = 0;
}

__global__ void fill_kernel(const int* __restrict__ src, const int* __restrict__ dst,
                            const int* __restrict__ rowptr, int* __restrict__ cursor,
                            int* __restrict__ col) {
    int e = blockIdx.x * blockDim.x + threadIdx.x;
    if (e < N_EDGES) {
        int d = dst[e];
        int pos = atomicAdd(&cursor[d], 1);
        col[rowptr[d] + pos] = src[e];
    }
}

// ---------------------------------------------------------------- prep: 3x wsplit (B hi/lo) + x cast (bf16)

__device__ inline void wsplit_one(const float* __restrict__ Ws, const float* __restrict__ Wn,
                                  short* __restrict__ Wh, short* __restrict__ Wl,
                                  int nout, int idx) {
    int c = idx >> 8, k = idx & 255;
    float v = (k < 128) ? Ws[(size_t)k * nout + c] : Wn[(size_t)(k - 128) * nout + c];
    ushort hi = f2bf(v);
    Wh[idx] = (short)hi;
    Wl[idx] = (short)f2bf(v - bf2f(hi));
}

__global__ void prep_kernel(const float* __restrict__ Ws0, const float* __restrict__ Wn0,
                            const float* __restrict__ Ws1, const float* __restrict__ Wn1,
                            const float* __restrict__ Ws2, const float* __restrict__ Wn2,
                            const float* __restrict__ x,
                            short* __restrict__ W0h, short* __restrict__ W0l,
                            short* __restrict__ W1h, short* __restrict__ W1l,
                            short* __restrict__ W2h, short* __restrict__ W2l,
                            ushort* __restrict__ nbh) {
    int b = blockIdx.x, t = threadIdx.x;
    if (b < 128) {
        wsplit_one(Ws0, Wn0, W0h, W0l, 128, b * 256 + t);
    } else if (b < 256) {
        wsplit_one(Ws1, Wn1, W1h, W1l, 128, (b - 128) * 256 + t);
    } else if (b < 320) {
        wsplit_one(Ws2, Wn2, W2h, W2l, 64, (b - 256) * 256 + t);
    } else {
        int i = (b - 320) * 256 + t;          // 4 floats per thread
        if (i < N_NODES * 32) {
            f32x4 v = *(const f32x4*)(x + (size_t)i * 4);
            ushort4 h4;
            h4.x = f2bf(v[0]); h4.y = f2bf(v[1]);
            h4.z = f2bf(v[2]); h4.w = f2bf(v[3]);
            *(ushort4*)(nbh + (size_t)i * 4) = h4;
        }
    }
}

// ---------------------------------------------------------------- aggregate (bf16 gather -> bf16 agg)

__global__ __launch_bounds__(256) void aggregate_kernel(
    const ushort* __restrict__ hb, const int* __restrict__ rowptr,
    const int* __restrict__ col, const int* __restrict__ cnt,
    uint32_t* __restrict__ aggh)
{
    int node = blockIdx.x * 4 + (threadIdx.x >> 6);
    int l = threadIdx.x & 63;
    if (node >= N_NODES) return;
    const int half = l >> 5;          // 0 / 1
    const int c    = l & 31;          // uint2 chunk: cols 4c..4c+3

    int beg = rowptr[node], end = rowptr[node + 1];
    int mid = beg + ((end - beg + 1) >> 1);
    int e    = half ? mid : beg;
    int hend = half ? end : mid;

    f32x4 s = {0.f, 0.f, 0.f, 0.f};

#define ACCUM(U) do {                                                        \
        s[0] += __builtin_bit_cast(float, (U).x << 16);                      \
        s[1] += __builtin_bit_cast(float, (U).x & 0xffff0000u);              \
        s[2] += __builtin_bit_cast(float, (U).y << 16);                      \
        s[3] += __builtin_bit_cast(float, (U).y & 0xffff0000u);              \
    } while (0)

    for (; e + 3 < hend; e += 4) {
        uint2 u0 = *(const uint2*)&hb[(size_t)col[e]     * 128 + c * 4];
        uint2 u1 = *(const uint2*)&hb[(size_t)col[e + 1] * 128 + c * 4];
        uint2 u2 = *(const uint2*)&hb[(size_t)col[e + 2] * 128 + c * 4];
        uint2 u3 = *(const uint2*)&hb[(size_t)col[e + 3] * 128 + c * 4];
        ACCUM(u0); ACCUM(u1); ACCUM(u2); ACCUM(u3);
    }
    for (; e < hend; ++e) {
        uint2 u = *(const uint2*)&hb[(size_t)col[e] * 128 + c * 4];
        ACCUM(u);
    }
#undef ACCUM

    s[0] += __shfl_xor(s[0], 32);
    s[1] += __shfl_xor(s[1], 32);
    s[2] += __shfl_xor(s[2], 32);
    s[3] += __shfl_xor(s[3], 32);

    if (half == 0) {
        float dinv = 1.0f / (float)max(cnt[node], 1);
        ushort h0 = f2bf(s[0] * dinv), h1 = f2bf(s[1] * dinv);
        ushort h2 = f2bf(s[2] * dinv), h3 = f2bf(s[3] * dinv);
        uint2 wh = { (uint32_t)h0 | ((uint32_t)h1 << 16), (uint32_t)h2 | ((uint32_t)h3 << 16) };
        ((uint2*)aggh)[(size_t)node * 32 + c] = wh;
    }
}

// ---------------------------------------------------------------- combine GEMM v9
// out[n,j] = relu([h|agg][n,:] @ Wcat[:,j] + b), K=256; A plain bf16,
// B hi/lo in LDS (acc += ah*bh + ah*bl).
// KEY CHANGE vs v5-v8: __launch_bounds__(256, 4) raises the VGPR cap to 128
// (LDS already caps 4 blocks/CU, so the compiler's default 8-wave/EU VGPR
// budget of 64 bought nothing and forced it to sink the prefetch — VGPR
// stuck at 48-52 for 3 rounds). All 16 A-loads (8 k-steps x 2 row-frags)
// are issued upfront into named registers (~64 VGPR payload); one global
// latency covers the whole k-loop. 392 rowblks = 8 x 49 -> exact XCD map.

template <int NOUT, int CB, bool RELU, bool FINAL>
__global__ __launch_bounds__(256, 4) void combine_mfma9(
    const ushort* __restrict__ nbh, const ushort* __restrict__ aggh,
    const short* __restrict__ Wth, const short* __restrict__ Wtl,
    const float* __restrict__ bias, float* __restrict__ out,
    ushort* __restrict__ oh)
{
    __shared__ __attribute__((aligned(16))) short Bh[32 * 33 * 8];
    __shared__ __attribute__((aligned(16))) short Bl[32 * 33 * 8];

    // ---- exact XCD-aware mapping: 392 rowblks = 8 * 49
    const int id  = blockIdx.x;          // grid = 392*CB
    const int xcd = id & 7;
    const int k   = id >> 3;
    const int row0    = (xcd * 49 + k / CB) * 128;
    const int colbase = (k % CB) * 32;

    const int tid  = threadIdx.x;
    const int lane = tid & 63;
    const int wave = tid >> 6;           // 0..3
    const int rr = lane & 15;
    const int kq = lane >> 4;            // 0..3

    const size_t arow0 = (size_t)(row0 + wave * 32 + rr) * 128;
    const size_t arow1 = arow0 + (size_t)16 * 128;

    // ---- B global loads first (so the ds_write's vmcnt only drains B)
    const int bcol = tid >> 3;
    const int bkc0 = (tid & 7) * 4;
    const short* gh = Wth + (size_t)(colbase + bcol) * 256 + bkc0 * 8;
    const short* gl = Wtl + (size_t)(colbase + bcol) * 256 + bkc0 * 8;
    bf16x8 tb0 = *(const bf16x8*)(gh);
    bf16x8 tb1 = *(const bf16x8*)(gh + 8);
    bf16x8 tb2 = *(const bf16x8*)(gh + 16);
    bf16x8 tb3 = *(const bf16x8*)(gh + 24);
    bf16x8 tl0 = *(const bf16x8*)(gl);
    bf16x8 tl1 = *(const bf16x8*)(gl + 8);
    bf16x8 tl2 = *(const bf16x8*)(gl + 16);
    bf16x8 tl3 = *(const bf16x8*)(gl + 24);

    // ---- ALL 16 A loads upfront, named registers (static indices, rule #20)
#define DECLA(KS) \
    const ushort* bs##KS = ((KS) < 4) ? nbh : aggh;                              \
    bf16x8 aA##KS = *(const bf16x8*)(bs##KS + arow0 + ((KS) & 3) * 32 + kq * 8); \
    bf16x8 aB##KS = *(const bf16x8*)(bs##KS + arow1 + ((KS) & 3) * 32 + kq * 8);
    DECLA(0) DECLA(1) DECLA(2) DECLA(3) DECLA(4) DECLA(5) DECLA(6) DECLA(7)
#undef DECLA

    // ---- stage B to LDS
    ((bf16x8*)Bh)[bcol * 33 + bkc0 + 0] = tb0;
    ((bf16x8*)Bh)[bcol * 33 + bkc0 + 1] = tb1;
    ((bf16x8*)Bh)[bcol * 33 + bkc0 + 2] = tb2;
    ((bf16x8*)Bh)[bcol * 33 + bkc0 + 3] = tb3;
    ((bf16x8*)Bl)[bcol * 33 + bkc0 + 0] = tl0;
    ((bf16x8*)Bl)[bcol * 33 + bkc0 + 1] = tl1;
    ((bf16x8*)Bl)[bcol * 33 + bkc0 + 2] = tl2;
    ((bf16x8*)Bl)[bcol * 33 + bkc0 + 3] = tl3;

    f32x4 acc[2][2];
    #pragma unroll
    for (int i = 0; i < 2; ++i)
        #pragma unroll
        for (int j = 0; j < 2; ++j)
            acc[i][j] = (f32x4){0.f, 0.f, 0.f, 0.f};

    __syncthreads();

#define COMPUTE(KS) do {                                                    \
        _Pragma("unroll")                                                   \
        for (int nj = 0; nj < 2; ++nj) {                                    \
            int colL = nj * 16 + rr;                                        \
            bf16x8 bh = ((const bf16x8*)Bh)[colL * 33 + (KS) * 4 + kq];     \
            bf16x8 bl = ((const bf16x8*)Bl)[colL * 33 + (KS) * 4 + kq];     \
            acc[0][nj] = __builtin_amdgcn_mfma_f32_16x16x32_bf16(aA##KS, bh, acc[0][nj], 0, 0, 0); \
            acc[0][nj] = __builtin_amdgcn_mfma_f32_16x16x32_bf16(aA##KS, bl, acc[0][nj], 0, 0, 0); \
            acc[1][nj] = __builtin_amdgcn_mfma_f32_16x16x32_bf16(aB##KS, bh, acc[1][nj], 0, 0, 0); \
            acc[1][nj] = __builtin_amdgcn_mfma_f32_16x16x32_bf16(aB##KS, bl, acc[1][nj], 0, 0, 0); \
        }                                                                   \
    } while (0)

    COMPUTE(0); COMPUTE(1); COMPUTE(2); COMPUTE(3);
    COMPUTE(4); COMPUTE(5); COMPUTE(6); COMPUTE(7);
#undef COMPUTE

    // ---- epilogue: D col=lane&15, row=(lane>>4)*4+r
    const int rg = lane >> 4;
    #pragma unroll
    for (int nj = 0; nj < 2; ++nj) {
        int colg = colbase + nj * 16 + rr;
        float bv = bias[colg];
        #pragma unroll
        for (int mi = 0; mi < 2; ++mi) {
            #pragma unroll
            for (int r = 0; r < 4; ++r) {
                int row = row0 + wave * 32 + mi * 16 + rg * 4 + r;
                if (row < N_NODES) {
                    float v = acc[mi][nj][r] + bv;
                    if (RELU) v = fmaxf(v, 0.f);
                    if (FINAL) out[(size_t)row * NOUT + colg] = v;
                    else       oh[(size_t)row * NOUT + colg] = f2bf(v);
                }
            }
        }
    }
}

// ---------------------------------------------------------------- launch

extern "C" void kernel_launch(void* const* d_in, const int* in_sizes, int n_in,
                              void* d_out, int out_size, void* d_ws, size_t ws_size,
                              hipStream_t stream) {
    const float* x   = (const float*)d_in[0];
    const int*   src = (const int*)d_in[1];
    const int*   dst = (const int*)d_in[2];
    const float* Ws0 = (const float*)d_in[3];
    const float* Wn0 = (const float*)d_in[4];
    const float* b0  = (const float*)d_in[5];
    const float* Ws1 = (const float*)d_in[6];
    const float* Wn1 = (const float*)d_in[7];
    const float* b1  = (const float*)d_in[8];
    const float* Ws2 = (const float*)d_in[9];
    const float* Wn2 = (const float*)d_in[10];
    const float* b2  = (const float*)d_in[11];
    float* out = (float*)d_out;

    char* p = (char*)d_ws;
    auto alloc = [&](size_t bytes) {
        char* r = p;
        p += (bytes + 255) & ~(size_t)255;
        return r;
    };
    int*      cnt      = (int*)alloc((size_t)N_NODES * 4);
    int*      cursor   = (int*)alloc((size_t)N_NODES * 4);
    int*      rowptr   = (int*)alloc((size_t)(N_NODES + 1) * 4);
    int*      col      = (int*)alloc((size_t)N_EDGES * 4);
    int*      partials = (int*)alloc((size_t)NPART * 4);
    int*      offsets  = (int*)alloc((size_t)NPART * 4);
    uint32_t* aggh     = (uint32_t*)alloc((size_t)PADROWS * 64 * 4);
    ushort*   nbh0     = (ushort*)alloc((size_t)PADROWS * 128 * 2);
    ushort*   nbh1     = (ushort*)alloc((size_t)PADROWS * 128 * 2);
    short*    Wt0_hi   = (short*)alloc((size_t)128 * 256 * 2);
    short*    Wt0_lo   = (short*)alloc((size_t)128 * 256 * 2);
    short*    Wt1_hi   = (short*)alloc((size_t)128 * 256 * 2);
    short*    Wt1_lo   = (short*)alloc((size_t)128 * 256 * 2);
    short*    Wt2_hi   = (short*)alloc((size_t)64 * 256 * 2);
    short*    Wt2_lo   = (short*)alloc((size_t)64 * 256 * 2);

    // CSR build
    zero2_kernel<<<NPART, 256, 0, stream>>>(cnt, cursor);
    count_kernel<<<(N_EDGES + 255) / 256, 256, 0, stream>>>(dst, cnt);
    scan_part <<<NPART, 256, 0, stream>>>(cnt, partials);
    scan_mid  <<<1, 256, 0, stream>>>(partials, offsets);
    scan_final<<<NPART, 256, 0, stream>>>(cnt, offsets, rowptr);
    fill_kernel<<<(N_EDGES + 255) / 256, 256, 0, stream>>>(src, dst, rowptr, cursor, col);

    // weight prep (hi/lo) + x cast (bf16), single launch
    prep_kernel<<<320 + (N_NODES * 32 + 255) / 256, 256, 0, stream>>>(
        Ws0, Wn0, Ws1, Wn1, Ws2, Wn2, x,
        Wt0_hi, Wt0_lo, Wt1_hi, Wt1_lo, Wt2_hi, Wt2_lo, nbh0);

    const int AGB = (N_NODES + 3) / 4;        // 12500

    // layer 0
    aggregate_kernel<<<AGB, 256, 0, stream>>>(nbh0, rowptr, col, cnt, aggh);
    combine_mfma9<128, 4, true, false><<<392 * 4, 256, 0, stream>>>(
        nbh0, (const ushort*)aggh, Wt0_hi, Wt0_lo, b0, nullptr, nbh1);
    // layer 1
    aggregate_kernel<<<AGB, 256, 0, stream>>>(nbh1, rowptr, col, cnt, aggh);
    combine_mfma9<128, 4, true, false><<<392 * 4, 256, 0, stream>>>(
        nbh1, (const ushort*)aggh, Wt1_hi, Wt1_lo, b1, nullptr, nbh0);
    // layer 2
    aggregate_kernel<<<AGB, 256, 0, stream>>>(nbh0, rowptr, col, cnt, aggh);
    combine_mfma9<64, 2, false, true><<<392 * 2, 256, 0, stream>>>(
        nbh0, (const ushort*)aggh, Wt2_hi, Wt2_lo, b2, out, nullptr);
}

// Round 12
// 214.221 us; speedup vs baseline: 1.0624x; 1.0624x over previous
//
#include <hip/hip_runtime.h>

#define N_NODES 50000
#define PADROWS 50176   // 196*256, branchless A loads (256-row tiles)
#define N_EDGES 600000
#define NPART 196   // ceil(50000/256)

using f32x4  = __attribute__((ext_vector_type(4))) float;
using bf16x8 = __attribute__((ext_vector_type(8))) short;

__device__ inline ushort f2bf(float f) {
    uint32_t u = __builtin_bit_cast(uint32_t, f);
    uint32_t r = (u + 0x7FFFu + ((u >> 16) & 1u)) >> 16;
    return (ushort)r;
}
__device__ inline float bf2f(ushort h) {
    uint32_t u = ((uint32_t)h) << 16;
    return __builtin_bit_cast(float, u);
}

// ---------------------------------------------------------------- zero

__global__ void zero2_kernel(int* __restrict__ a, int* __restrict__ b) {
    int i = blockIdx.x * 256 + threadIdx.x;
    if (i < N_NODES) { a[i] = 0; b[i] = 0; }
}

// ---------------------------------------------------------------- CSR build

__global__ void count_kernel(const int* __restrict__ dst, int* __restrict__ cnt) {
    int e = blockIdx.x * blockDim.x + threadIdx.x;
    if (e < N_EDGES) atomicAdd(&cnt[dst[e]], 1);
}

__global__ void scan_part(const int* __restrict__ cnt, int* __restrict__ partials) {
    __shared__ int sm[256];
    int b = blockIdx.x, t = threadIdx.x;
    int i = b * 256 + t;
    sm[t] = (i < N_NODES) ? cnt[i] : 0;
    __syncthreads();
    for (int off = 128; off > 0; off >>= 1) {
        if (t < off) sm[t] += sm[t + off];
        __syncthreads();
    }
    if (t == 0) partials[b] = sm[0];
}

// scan_final now self-computes its block offset from partials (scan_mid dropped)
__global__ void scan_final(const int* __restrict__ cnt, const int* __restrict__ partials,
                           int* __restrict__ rowptr) {
    __shared__ int sp[256];
    __shared__ int sm[256];
    int b = blockIdx.x, t = threadIdx.x;
    sp[t] = (t < NPART) ? partials[t] : 0;
    __syncthreads();
    for (int off = 1; off < 256; off <<= 1) {
        int u = (t >= off) ? sp[t - off] : 0;
        __syncthreads();
        sp[t] += u;
        __syncthreads();
    }
    int offset = (b == 0) ? 0 : sp[b - 1];

    int i = b * 256 + t;
    int v = (i < N_NODES) ? cnt[i] : 0;
    sm[t] = v;
    __syncthreads();
    for (int off = 1; off < 256; off <<= 1) {
        int u = (t >= off) ? sm[t - off] : 0;
        __syncthreads();
        sm[t] += u;
        __syncthreads();
    }
    if (i < N_NODES) rowptr[i + 1] = sm[t] + offset;
    if (i == 0) rowptr[0] = 0;
}

__global__ void fill_kernel(const int* __restrict__ src, const int* __restrict__ dst,
                            const int* __restrict__ rowptr, int* __restrict__ cursor,
                            int* __restrict__ col) {
    int e = blockIdx.x * blockDim.x + threadIdx.x;
    if (e < N_EDGES) {
        int d = dst[e];
        int pos = atomicAdd(&cursor[d], 1);
        col[rowptr[d] + pos] = src[e];
    }
}

// ---------------------------------------------------------------- prep: 3x wsplit (B hi/lo) + x cast (bf16)

__device__ inline void wsplit_one(const float* __restrict__ Ws, const float* __restrict__ Wn,
                                  short* __restrict__ Wh, short* __restrict__ Wl,
                                  int nout, int idx) {
    int c = idx >> 8, k = idx & 255;
    float v = (k < 128) ? Ws[(size_t)k * nout + c] : Wn[(size_t)(k - 128) * nout + c];
    ushort hi = f2bf(v);
    Wh[idx] = (short)hi;
    Wl[idx] = (short)f2bf(v - bf2f(hi));
}

__global__ void prep_kernel(const float* __restrict__ Ws0, const float* __restrict__ Wn0,
                            const float* __restrict__ Ws1, const float* __restrict__ Wn1,
                            const float* __restrict__ Ws2, const float* __restrict__ Wn2,
                            const float* __restrict__ x,
                            short* __restrict__ W0h, short* __restrict__ W0l,
                            short* __restrict__ W1h, short* __restrict__ W1l,
                            short* __restrict__ W2h, short* __restrict__ W2l,
                            ushort* __restrict__ nbh) {
    int b = blockIdx.x, t = threadIdx.x;
    if (b < 128) {
        wsplit_one(Ws0, Wn0, W0h, W0l, 128, b * 256 + t);
    } else if (b < 256) {
        wsplit_one(Ws1, Wn1, W1h, W1l, 128, (b - 128) * 256 + t);
    } else if (b < 320) {
        wsplit_one(Ws2, Wn2, W2h, W2l, 64, (b - 256) * 256 + t);
    } else {
        int i = (b - 320) * 256 + t;          // 4 floats per thread
        if (i < N_NODES * 32) {
            f32x4 v = *(const f32x4*)(x + (size_t)i * 4);
            ushort4 h4;
            h4.x = f2bf(v[0]); h4.y = f2bf(v[1]);
            h4.z = f2bf(v[2]); h4.w = f2bf(v[3]);
            *(ushort4*)(nbh + (size_t)i * 4) = h4;
        }
    }
}

// ---------------------------------------------------------------- aggregate (bf16 gather -> bf16 agg)

__global__ __launch_bounds__(256) void aggregate_kernel(
    const ushort* __restrict__ hb, const int* __restrict__ rowptr,
    const int* __restrict__ col, const int* __restrict__ cnt,
    uint32_t* __restrict__ aggh)
{
    int node = blockIdx.x * 4 + (threadIdx.x >> 6);
    int l = threadIdx.x & 63;
    if (node >= N_NODES) return;
    const int half = l >> 5;          // 0 / 1
    const int c    = l & 31;          // uint2 chunk: cols 4c..4c+3

    int beg = rowptr[node], end = rowptr[node + 1];
    int mid = beg + ((end - beg + 1) >> 1);
    int e    = half ? mid : beg;
    int hend = half ? end : mid;

    f32x4 s = {0.f, 0.f, 0.f, 0.f};

#define ACCUM(U) do {                                                        \
        s[0] += __builtin_bit_cast(float, (U).x << 16);                      \
        s[1] += __builtin_bit_cast(float, (U).x & 0xffff0000u);              \
        s[2] += __builtin_bit_cast(float, (U).y << 16);                      \
        s[3] += __builtin_bit_cast(float, (U).y & 0xffff0000u);              \
    } while (0)

    for (; e + 3 < hend; e += 4) {
        uint2 u0 = *(const uint2*)&hb[(size_t)col[e]     * 128 + c * 4];
        uint2 u1 = *(const uint2*)&hb[(size_t)col[e + 1] * 128 + c * 4];
        uint2 u2 = *(const uint2*)&hb[(size_t)col[e + 2] * 128 + c * 4];
        uint2 u3 = *(const uint2*)&hb[(size_t)col[e + 3] * 128 + c * 4];
        ACCUM(u0); ACCUM(u1); ACCUM(u2); ACCUM(u3);
    }
    for (; e < hend; ++e) {
        uint2 u = *(const uint2*)&hb[(size_t)col[e] * 128 + c * 4];
        ACCUM(u);
    }
#undef ACCUM

    s[0] += __shfl_xor(s[0], 32);
    s[1] += __shfl_xor(s[1], 32);
    s[2] += __shfl_xor(s[2], 32);
    s[3] += __shfl_xor(s[3], 32);

    if (half == 0) {
        float dinv = 1.0f / (float)max(cnt[node], 1);
        ushort h0 = f2bf(s[0] * dinv), h1 = f2bf(s[1] * dinv);
        ushort h2 = f2bf(s[2] * dinv), h3 = f2bf(s[3] * dinv);
        uint2 wh = { (uint32_t)h0 | ((uint32_t)h1 << 16), (uint32_t)h2 | ((uint32_t)h3 << 16) };
        ((uint2*)aggh)[(size_t)node * 32 + c] = wh;
    }
}

// ---------------------------------------------------------------- combine GEMM v10
// Tile 256 rows x 64 cols, 512 thr / 8 waves, per-wave mi2 x nj4 (128 MFMA/wave
// vs 64 before). Rationale: pipes all <20% busy; the cost is per-wave fixed
// latency (B-stage, barrier, per-KS dependency chains) — double the MFMAs it
// amortizes over while A-loads/wave stay constant. Scheduling experiments
// (R7/8/9/11) were all null; work-amortization (R4, R10) always paid.
// A plain bf16, B hi/lo in 67.6KB LDS (2 blocks/CU), single-generation grid.

template <int NOUT, int CB, bool RELU, bool FINAL>
__global__ __launch_bounds__(512, 4) void combine_mfma10(
    const ushort* __restrict__ nbh, const ushort* __restrict__ aggh,
    const short* __restrict__ Wth, const short* __restrict__ Wtl,
    const float* __restrict__ bias, float* __restrict__ out,
    ushort* __restrict__ oh)
{
    __shared__ __attribute__((aligned(16))) short Bh[64 * 33 * 8];
    __shared__ __attribute__((aligned(16))) short Bl[64 * 33 * 8];

    // ---- bijective XCD-aware mapping: 196 rowblks = 4*25 + 4*24
    const int id  = blockIdx.x;          // grid = 8 * 25 * CB
    const int xcd = id & 7;
    const int k   = id >> 3;
    const int rb  = k / CB;
    const int cnt_x = (xcd < 4) ? 25 : 24;
    if (rb >= cnt_x) return;             // uniform across block
    const int base  = (xcd < 4) ? xcd * 25 : 100 + (xcd - 4) * 24;
    const int row0    = (base + rb) * 256;
    const int colbase = (k % CB) * 64;

    const int tid  = threadIdx.x;
    const int lane = tid & 63;
    const int wave = tid >> 6;           // 0..7
    const int rr = lane & 15;
    const int kq = lane >> 4;            // 0..3

    // ---- stage B once: 64 cols x 32 chunks, hi+lo
    {
        int col = tid >> 3;              // 0..63
        int kc0 = (tid & 7) * 4;
        const short* gh = Wth + (size_t)(colbase + col) * 256 + kc0 * 8;
        const short* gl = Wtl + (size_t)(colbase + col) * 256 + kc0 * 8;
        #pragma unroll
        for (int j = 0; j < 4; ++j) {
            ((bf16x8*)Bh)[col * 33 + kc0 + j] = *(const bf16x8*)(gh + j * 8);
            ((bf16x8*)Bl)[col * 33 + kc0 + j] = *(const bf16x8*)(gl + j * 8);
        }
    }

    const size_t arow0 = (size_t)(row0 + wave * 32 + rr) * 128;
    const size_t arow1 = arow0 + (size_t)16 * 128;

    f32x4 acc[2][4];
    #pragma unroll
    for (int i = 0; i < 2; ++i)
        #pragma unroll
        for (int j = 0; j < 4; ++j)
            acc[i][j] = (f32x4){0.f, 0.f, 0.f, 0.f};

    __syncthreads();

#define COMPUTE(KS) do {                                                    \
        const ushort* bs_ = ((KS) < 4) ? nbh : aggh;                        \
        const int kf_ = ((KS) & 3) * 32 + kq * 8;                           \
        bf16x8 aA = *(const bf16x8*)(bs_ + arow0 + kf_);                    \
        bf16x8 aB = *(const bf16x8*)(bs_ + arow1 + kf_);                    \
        _Pragma("unroll")                                                   \
        for (int nj = 0; nj < 4; ++nj) {                                    \
            int colL = nj * 16 + rr;                                        \
            bf16x8 bh = ((const bf16x8*)Bh)[colL * 33 + (KS) * 4 + kq];     \
            bf16x8 bl = ((const bf16x8*)Bl)[colL * 33 + (KS) * 4 + kq];     \
            acc[0][nj] = __builtin_amdgcn_mfma_f32_16x16x32_bf16(aA, bh, acc[0][nj], 0, 0, 0); \
            acc[0][nj] = __builtin_amdgcn_mfma_f32_16x16x32_bf16(aA, bl, acc[0][nj], 0, 0, 0); \
            acc[1][nj] = __builtin_amdgcn_mfma_f32_16x16x32_bf16(aB, bh, acc[1][nj], 0, 0, 0); \
            acc[1][nj] = __builtin_amdgcn_mfma_f32_16x16x32_bf16(aB, bl, acc[1][nj], 0, 0, 0); \
        }                                                                   \
    } while (0)

    COMPUTE(0); COMPUTE(1); COMPUTE(2); COMPUTE(3);
    COMPUTE(4); COMPUTE(5); COMPUTE(6); COMPUTE(7);
#undef COMPUTE

    // ---- epilogue: D col=lane&15, row=(lane>>4)*4+r
    const int rg = lane >> 4;
    #pragma unroll
    for (int nj = 0; nj < 4; ++nj) {
        int colg = colbase + nj * 16 + rr;
        float bv = bias[colg];
        #pragma unroll
        for (int mi = 0; mi < 2; ++mi) {
            #pragma unroll
            for (int r = 0; r < 4; ++r) {
                int row = row0 + wave * 32 + mi * 16 + rg * 4 + r;
                if (row < N_NODES) {
                    float v = acc[mi][nj][r] + bv;
                    if (RELU) v = fmaxf(v, 0.f);
                    if (FINAL) out[(size_t)row * NOUT + colg] = v;
                    else       oh[(size_t)row * NOUT + colg] = f2bf(v);
                }
            }
        }
    }
}

// ---------------------------------------------------------------- launch

extern "C" void kernel_launch(void* const* d_in, const int* in_sizes, int n_in,
                              void* d_out, int out_size, void* d_ws, size_t ws_size,
                              hipStream_t stream) {
    const float* x   = (const float*)d_in[0];
    const int*   src = (const int*)d_in[1];
    const int*   dst = (const int*)d_in[2];
    const float* Ws0 = (const float*)d_in[3];
    const float* Wn0 = (const float*)d_in[4];
    const float* b0  = (const float*)d_in[5];
    const float* Ws1 = (const float*)d_in[6];
    const float* Wn1 = (const float*)d_in[7];
    const float* b1  = (const float*)d_in[8];
    const float* Ws2 = (const float*)d_in[9];
    const float* Wn2 = (const float*)d_in[10];
    const float* b2  = (const float*)d_in[11];
    float* out = (float*)d_out;

    char* p = (char*)d_ws;
    auto alloc = [&](size_t bytes) {
        char* r = p;
        p += (bytes + 255) & ~(size_t)255;
        return r;
    };
    int*      cnt      = (int*)alloc((size_t)N_NODES * 4);
    int*      cursor   = (int*)alloc((size_t)N_NODES * 4);
    int*      rowptr   = (int*)alloc((size_t)(N_NODES + 1) * 4);
    int*      col      = (int*)alloc((size_t)N_EDGES * 4);
    int*      partials = (int*)alloc((size_t)NPART * 4);
    uint32_t* aggh     = (uint32_t*)alloc((size_t)PADROWS * 64 * 4);
    ushort*   nbh0     = (ushort*)alloc((size_t)PADROWS * 128 * 2);
    ushort*   nbh1     = (ushort*)alloc((size_t)PADROWS * 128 * 2);
    short*    Wt0_hi   = (short*)alloc((size_t)128 * 256 * 2);
    short*    Wt0_lo   = (short*)alloc((size_t)128 * 256 * 2);
    short*    Wt1_hi   = (short*)alloc((size_t)128 * 256 * 2);
    short*    Wt1_lo   = (short*)alloc((size_t)128 * 256 * 2);
    short*    Wt2_hi   = (short*)alloc((size_t)64 * 256 * 2);
    short*    Wt2_lo   = (short*)alloc((size_t)64 * 256 * 2);

    // CSR build (scan_mid merged into scan_final)
    zero2_kernel<<<NPART, 256, 0, stream>>>(cnt, cursor);
    count_kernel<<<(N_EDGES + 255) / 256, 256, 0, stream>>>(dst, cnt);
    scan_part <<<NPART, 256, 0, stream>>>(cnt, partials);
    scan_final<<<NPART, 256, 0, stream>>>(cnt, partials, rowptr);
    fill_kernel<<<(N_EDGES + 255) / 256, 256, 0, stream>>>(src, dst, rowptr, cursor, col);

    // weight prep (hi/lo) + x cast (bf16), single launch
    prep_kernel<<<320 + (N_NODES * 32 + 255) / 256, 256, 0, stream>>>(
        Ws0, Wn0, Ws1, Wn1, Ws2, Wn2, x,
        Wt0_hi, Wt0_lo, Wt1_hi, Wt1_lo, Wt2_hi, Wt2_lo, nbh0);

    const int AGB = (N_NODES + 3) / 4;        // 12500

    // layer 0
    aggregate_kernel<<<AGB, 256, 0, stream>>>(nbh0, rowptr, col, cnt, aggh);
    combine_mfma10<128, 2, true, false><<<8 * 25 * 2, 512, 0, stream>>>(
        nbh0, (const ushort*)aggh, Wt0_hi, Wt0_lo, b0, nullptr, nbh1);
    // layer 1
    aggregate_kernel<<<AGB, 256, 0, stream>>>(nbh1, rowptr, col, cnt, aggh);
    combine_mfma10<128, 2, true, false><<<8 * 25 * 2, 512, 0, stream>>>(
        nbh1, (const ushort*)aggh, Wt1_hi, Wt1_lo, b1, nullptr, nbh0);
    // layer 2
    aggregate_kernel<<<AGB, 256, 0, stream>>>(nbh0, rowptr, col, cnt, aggh);
    combine_mfma10<64, 1, false, true><<<8 * 25 * 1, 512, 0, stream>>>(
        nbh0, (const ushort*)aggh, Wt2_hi, Wt2_lo, b2, out, nullptr);
}